// Round 1
// 236.347 us; speedup vs baseline: 1.0039x; 1.0039x over previous
//
#include <hip/hip_runtime.h>

// R6: (a) gemm: 32-col tiles + depth-2 register prefetch (~1100 cyc in flight
//     vs ~900 cyc HBM latency; R5 had ~300 cyc -> latency-bound), v_cvt_pk_bf16_f32
//     staging (4 insts vs ~36 VALU manual RNE, bit-identical rounding);
//     (b) thr computed per-block in gemm (x is L2-hot) -> init is a pure zero stub;
//     (c) fallback fused into reduce -> 4 launches -> 3.
// Exactness unchanged: adaptive gate z*||x_row|| + candidate cap + brute-force path.
#define BROWS 256
#define NCOLS 131072
#define DDIM  128
#define K     5
#define MARGIN 0.3f

#define NBLK  512                // gemm grid: 2 blocks/CU
#define CPB   (NCOLS / NBLK)     // 256 cols per block
#define TCOLS 32                 // cols per tile
#define NIT   (CPB / TCOLS)      // 8 iters
#define ZGATE 3.4f               // per-row gate z-score: E[count] ~ 44
#define CAP   128                // per-row candidate capacity
#define YSTR  68                 // ybf col stride in words (64 data + 4 pad)

typedef __attribute__((ext_vector_type(8))) __bf16 bf16x8;
typedef __attribute__((ext_vector_type(4))) float f32x4;
typedef __attribute__((ext_vector_type(4))) unsigned int u32x4;

// two fp32 -> packed bf16 word (lo=a, hi=b), RNE — single HW instruction
__device__ __forceinline__ unsigned pack_bf16(float a, float b) {
    unsigned r;
    asm("v_cvt_pk_bf16_f32 %0, %1, %2" : "=v"(r) : "v"(a), "v"(b));
    return r;
}

__device__ __forceinline__ u32x4 pack8(const float4& a, const float4& b) {
    u32x4 t;
    t[0] = pack_bf16(a.x, a.y); t[1] = pack_bf16(a.z, a.w);
    t[2] = pack_bf16(b.x, b.y); t[3] = pack_bf16(b.z, b.w);
    return t;
}

// ---- Pass 0: zero cnt + out (thr moved into gemm) ---------------------------
__global__ __launch_bounds__(256) void init_kernel(
    int* __restrict__ cnt, float* __restrict__ out)
{
    const int t = threadIdx.x;
    cnt[t] = 0;
    if (t == 0) out[0] = 0.f;
}

// ---- Pass 1: bf16 MFMA gemm + adaptive threshold collection -----------------
__global__ __launch_bounds__(256, 2) void gemm_collect_kernel(
    const float* __restrict__ x, const float* __restrict__ y,
    int* __restrict__ cnt, float* __restrict__ bufv, int* __restrict__ bufc)
{
    __shared__ unsigned ybf[2][TCOLS * YSTR];   // double-buffered bf16 y tile, 2x8.5 KB
    __shared__ float sthr[BROWS];

    const int tid   = threadIdx.x;
    const int lane  = tid & 63;
    const int quad  = lane >> 4;
    const int l15   = lane & 15;
    const int wrow0 = tid & 192;             // wave_id*64
    const int col0  = blockIdx.x * CPB;

    // per-row gate thresholds, computed redundantly per block (x is L2-resident)
    {
        const float* xp = x + (size_t)tid * DDIM;
        float s = 0.f;
#pragma unroll
        for (int k = 0; k < DDIM; k += 4) {
            const float4 v = *(const float4*)(xp + k);
            s = fmaf(v.x, v.x, s); s = fmaf(v.y, v.y, s);
            s = fmaf(v.z, v.z, s); s = fmaf(v.w, v.w, s);
        }
        sthr[tid] = ZGATE * sqrtf(s);
    }

    // A fragments: x fp32 -> bf16 once, register-resident. A[m=l15][k=quad*8+j].
    bf16x8 af[4][4];
#pragma unroll
    for (int mt = 0; mt < 4; ++mt) {
        const float* xp = x + (size_t)(wrow0 + mt * 16 + l15) * DDIM + quad * 8;
#pragma unroll
        for (int s = 0; s < 4; ++s) {
            const float4 a = *(const float4*)(xp + s * 32);
            const float4 b = *(const float4*)(xp + s * 32 + 4);
            const u32x4 t = pack8(a, b);
            af[mt][s] = __builtin_bit_cast(bf16x8, t);
        }
    }

    // staging: thread (scol, skk) loads 16 fp32 (64B) of one col, writes 2 b128
    const int scol = tid >> 3;               // 0..31
    const int skk  = tid & 7;                // 0..7
    const float* ysrc = y + (size_t)(col0 + scol) * DDIM + skk * 16;
    const unsigned sdst = scol * YSTR + skk * 8;        // word offset in a buffer
    const unsigned frag_off = l15 * YSTR + quad * 4;    // + cg*16*YSTR + s*16

    // depth-2 register prefetch: tile t lives in sl[t&1]
    float4 sl[2][4];
#pragma unroll
    for (int q = 0; q < 4; ++q) sl[0][q] = *(const float4*)(ysrc + q * 4);
#pragma unroll
    for (int q = 0; q < 4; ++q) sl[1][q] = *(const float4*)(ysrc + TCOLS * DDIM + q * 4);
    {
        u32x4* d = (u32x4*)(&ybf[0][0] + sdst);
        d[0] = pack8(sl[0][0], sl[0][1]);
        d[1] = pack8(sl[0][2], sl[0][3]);
    }
    __syncthreads();                         // covers sthr + tile0 LDS write

    // per-row gate thresholds for the 16 acc rows this lane owns
    float thrv[16];
#pragma unroll
    for (int mt = 0; mt < 4; ++mt)
#pragma unroll
        for (int r = 0; r < 4; ++r)
            thrv[mt * 4 + r] = sthr[wrow0 + mt * 16 + quad * 4 + r];

#pragma unroll 2
    for (int it = 0; it < NIT; ++it) {
        if (it + 2 < NIT) {                  // issue tile it+2 loads (slot it&1 is free)
            const float* yn = ysrc + (size_t)(it + 2) * TCOLS * DDIM;
#pragma unroll
            for (int q = 0; q < 4; ++q) sl[it & 1][q] = *(const float4*)(yn + q * 4);
        }
        if (it) __syncthreads();             // ybf[it&1] visible; prev reads done

        const unsigned* yb = &ybf[it & 1][0];

        // col-group 0
        f32x4 acc[2][4];
        bf16x8 bfrag[4];
#pragma unroll
        for (int s = 0; s < 4; ++s)
            bfrag[s] = __builtin_bit_cast(bf16x8, *(const u32x4*)(yb + frag_off + s * 16));
#pragma unroll
        for (int mt = 0; mt < 4; ++mt) acc[0][mt] = (f32x4){0.f, 0.f, 0.f, 0.f};
#pragma unroll
        for (int s = 0; s < 4; ++s)
#pragma unroll
            for (int mt = 0; mt < 4; ++mt)
                acc[0][mt] = __builtin_amdgcn_mfma_f32_16x16x32_bf16(af[mt][s], bfrag[s], acc[0][mt], 0, 0, 0);

        if (it + 1 < NIT) {                  // stage tile it+1 into the other buffer
            u32x4* d = (u32x4*)(&ybf[(it + 1) & 1][0] + sdst);
            d[0] = pack8(sl[(it + 1) & 1][0], sl[(it + 1) & 1][1]);
            d[1] = pack8(sl[(it + 1) & 1][2], sl[(it + 1) & 1][3]);
        }

        // col-group 1
#pragma unroll
        for (int s = 0; s < 4; ++s)
            bfrag[s] = __builtin_bit_cast(bf16x8, *(const u32x4*)(yb + 16 * YSTR + frag_off + s * 16));
#pragma unroll
        for (int mt = 0; mt < 4; ++mt) acc[1][mt] = (f32x4){0.f, 0.f, 0.f, 0.f};
#pragma unroll
        for (int s = 0; s < 4; ++s)
#pragma unroll
            for (int mt = 0; mt < 4; ++mt)
                acc[1][mt] = __builtin_amdgcn_mfma_f32_16x16x32_bf16(af[mt][s], bfrag[s], acc[1][mt], 0, 0, 0);

        // collect: lane's 16 acc values of group cg share col = col0+it*32+cg*16+l15.
#pragma unroll
        for (int cg = 0; cg < 2; ++cg) {
            float m = -1.f;
#pragma unroll
            for (int mt = 0; mt < 4; ++mt)
#pragma unroll
                for (int r = 0; r < 4; ++r)
                    m = fmaxf(m, acc[cg][mt][r] - thrv[mt * 4 + r]);
            if (m > 0.f) {
                const int col = col0 + it * TCOLS + cg * 16 + l15;
#pragma unroll
                for (int mt = 0; mt < 4; ++mt)
#pragma unroll
                    for (int r = 0; r < 4; ++r) {
                        const float v = acc[cg][mt][r];
                        if (v > thrv[mt * 4 + r]) {
                            const int row = wrow0 + mt * 16 + quad * 4 + r;
                            const int idx = atomicAdd(&cnt[row], 1);
                            if (idx < CAP) {
                                bufv[row * CAP + idx] = v;
                                bufc[row * CAP + idx] = col;
                            }
                        }
                    }
            }
        }
    }
}

// ---- shared epilogue helpers ------------------------------------------------
__device__ __forceinline__ void insert5(float* t5, float v) {
    if (v > t5[K - 1]) {
        float nv = v;
#pragma unroll
        for (int p = 0; p < K; ++p) {
            const bool gt = nv > t5[p];
            const float tv = t5[p];
            if (gt) { t5[p] = nv; nv = tv; }
        }
    }
}

__device__ __forceinline__ void merge5(float* __restrict__ t5, const float* __restrict__ src) {
#pragma unroll
    for (int p = 0; p < K; ++p) insert5(t5, src[p]);
}

__device__ __forceinline__ float epilogue(const float* t5, float sp) {
    float loss[K], logit[K];
#pragma unroll
    for (int p = 0; p < K; ++p) {
        loss[p]  = fmaxf(0.f, t5[p] - sp + MARGIN);
        logit[p] = (loss[p] != 0.f) ? t5[p] : 0.f;   // sim_n * mask, as reference
    }
    float mx = logit[0];
#pragma unroll
    for (int p = 1; p < K; ++p) mx = fmaxf(mx, logit[p]);
    float den = 0.f, num = 0.f;
#pragma unroll
    for (int p = 0; p < K; ++p) {
        const float e = __expf(logit[p] - mx);
        den += e;
        num += loss[p] * e;
    }
    return num / den;
}

// ---- Pass 2: per-row exact top-5 + loss; brute-force fallback fused in ------
__global__ __launch_bounds__(256) void reduce_kernel(
    const float* __restrict__ x, const float* __restrict__ y,
    const int* __restrict__ pos, const int* __restrict__ cnt,
    const float* __restrict__ bufv, const int* __restrict__ bufc,
    float* __restrict__ out)
{
    const int row = blockIdx.x;
    const int tid = threadIdx.x;
    __shared__ float sred[256];
    __shared__ float sv[256 * K];
    __shared__ float xr[DDIM];
    __shared__ int   sok;

    // sim_p = fp32 dot(x[row], y[pos[row]])
    const int prow = pos[row];
    float p = 0.f;
    if (tid < DDIM) p = x[row * DDIM + tid] * y[(size_t)prow * DDIM + tid];
    sred[tid] = p;
    __syncthreads();
    for (int s = 128; s >= 1; s >>= 1) {
        if (tid < s) sred[tid] += sred[tid + s];
        __syncthreads();
    }
    const float sp = sred[0];

    const int c = cnt[row];
    const int n = c < CAP ? c : CAP;
    float t5[K];
#pragma unroll
    for (int q = 0; q < K; ++q) t5[q] = -3.0e38f;
    if (tid < n && bufc[row * CAP + tid] != prow)
        t5[0] = bufv[row * CAP + tid];   // one entry per thread (CAP <= 256)

#pragma unroll
    for (int q = 0; q < K; ++q) sv[tid * K + q] = t5[q];
    __syncthreads();
    for (int s = 128; s >= 1; s >>= 1) {
        if (tid < s) {
            merge5(t5, &sv[(tid + s) * K]);
#pragma unroll
            for (int q = 0; q < K; ++q) sv[tid * K + q] = t5[q];
        }
        __syncthreads();
    }

    if (tid == 0) {
        // exact iff no overflow and >=5 valid survivors
        sok = (c <= CAP && t5[K - 1] > -1.0e38f) ? 1 : 0;
        if (sok) atomicAdd(out, epilogue(t5, sp) * (1.0f / (BROWS * K)));
    }
    __syncthreads();
    if (sok) return;

    // ---- brute-force insurance (statistically never taken; exactness) ------
    if (tid < DDIM) xr[tid] = x[row * DDIM + tid];
    __syncthreads();

#pragma unroll
    for (int q = 0; q < K; ++q) t5[q] = -3.0e38f;
    for (int col = tid; col < NCOLS; col += 256) {
        if (col == prow) continue;
        const float* yp = y + (size_t)col * DDIM;
        float d = 0.f;
        for (int k = 0; k < DDIM; ++k) d = fmaf(xr[k], yp[k], d);
        insert5(t5, d);
    }
#pragma unroll
    for (int q = 0; q < K; ++q) sv[tid * K + q] = t5[q];
    __syncthreads();
    for (int s = 128; s >= 1; s >>= 1) {
        if (tid < s) {
            merge5(t5, &sv[(tid + s) * K]);
#pragma unroll
            for (int q = 0; q < K; ++q) sv[tid * K + q] = t5[q];
        }
        __syncthreads();
    }
    if (tid == 0) atomicAdd(out, epilogue(t5, sp) * (1.0f / (BROWS * K)));
}

extern "C" void kernel_launch(void* const* d_in, const int* in_sizes, int n_in,
                              void* d_out, int out_size, void* d_ws, size_t ws_size,
                              hipStream_t stream) {
    const float* x  = (const float*)d_in[0];   // [256,128] fp32
    const float* y  = (const float*)d_in[1];   // [131072,128] fp32
    // d_in[2] (target) is redundant (one-hot of pos_inds) — never read.
    const int* pos  = (const int*)d_in[3];     // [256] int32
    // d_in[4] (num_neg) fixed at 5 — compile-time K.

    int*   cnt  = (int*)d_ws;                          // 256 ints
    float* bufv = (float*)(cnt + BROWS);               // 256*CAP floats (128 KB)
    int*   bufc = (int*)(bufv + (size_t)BROWS * CAP);  // 256*CAP ints

    init_kernel<<<dim3(1), 256, 0, stream>>>(cnt, (float*)d_out);
    gemm_collect_kernel<<<dim3(NBLK), 256, 0, stream>>>(x, y, cnt, bufv, bufc);
    reduce_kernel<<<dim3(BROWS), 256, 0, stream>>>(x, y, pos, cnt, bufv, bufc, (float*)d_out);
}

// Round 2
// 236.026 us; speedup vs baseline: 1.0052x; 1.0014x over previous
//
#include <hip/hip_runtime.h>

// R7: (a) init: 256x64 grid — block r zeroes cnt[r] AND computes simp[r] =
//     dot(x[r], y[pos[r]]) via wave shuffle (absorbs reduce's dot phase);
//     (b) reduce: top-5 merge via per-wave __shfl_xor butterfly (6 rounds)
//     + single 4-way LDS merge, replacing the 16-syncthreads LDS tree;
//     (c) gemm unchanged — at its 64 MiB read BW floor (~11-13 us).
// This is also the decisive test of the harness-floor hypothesis: if dur_us
// doesn't move, the window is 2x512MiB poison fills (86% HBM peak) + reset
// memsets, and we are at the roofline.
#define BROWS 256
#define NCOLS 131072
#define DDIM  128
#define K     5
#define MARGIN 0.3f

#define NBLK  512                // gemm grid: 2 blocks/CU
#define CPB   (NCOLS / NBLK)     // 256 cols per block
#define TCOLS 32                 // cols per tile
#define NIT   (CPB / TCOLS)      // 8 iters
#define ZGATE 3.4f               // per-row gate z-score: E[count] ~ 44
#define CAP   128                // per-row candidate capacity
#define YSTR  68                 // ybf col stride in words (64 data + 4 pad)

typedef __attribute__((ext_vector_type(8))) __bf16 bf16x8;
typedef __attribute__((ext_vector_type(4))) float f32x4;
typedef __attribute__((ext_vector_type(4))) unsigned int u32x4;

// two fp32 -> packed bf16 word (lo=a, hi=b), RNE — single HW instruction
__device__ __forceinline__ unsigned pack_bf16(float a, float b) {
    unsigned r;
    asm("v_cvt_pk_bf16_f32 %0, %1, %2" : "=v"(r) : "v"(a), "v"(b));
    return r;
}

__device__ __forceinline__ u32x4 pack8(const float4& a, const float4& b) {
    u32x4 t;
    t[0] = pack_bf16(a.x, a.y); t[1] = pack_bf16(a.z, a.w);
    t[2] = pack_bf16(b.x, b.y); t[3] = pack_bf16(b.z, b.w);
    return t;
}

// ---- Pass 0: zero cnt + out, compute sim_p per row --------------------------
__global__ __launch_bounds__(64) void init_kernel(
    const float* __restrict__ x, const float* __restrict__ y,
    const int* __restrict__ pos,
    int* __restrict__ cnt, float* __restrict__ simp, float* __restrict__ out)
{
    const int row  = blockIdx.x;
    const int lane = threadIdx.x;
    const int prow = pos[row];
    const float* xp = x + (size_t)row * DDIM;
    const float* yp = y + (size_t)prow * DDIM;
    float d = fmaf(xp[lane], yp[lane], xp[lane + 64] * yp[lane + 64]);
#pragma unroll
    for (int off = 32; off >= 1; off >>= 1) d += __shfl_xor(d, off);
    if (lane == 0) {
        simp[row] = d;
        cnt[row]  = 0;
        if (row == 0) out[0] = 0.f;
    }
}

// ---- Pass 1: bf16 MFMA gemm + adaptive threshold collection -----------------
__global__ __launch_bounds__(256, 2) void gemm_collect_kernel(
    const float* __restrict__ x, const float* __restrict__ y,
    int* __restrict__ cnt, float* __restrict__ bufv, int* __restrict__ bufc)
{
    __shared__ unsigned ybf[2][TCOLS * YSTR];   // double-buffered bf16 y tile, 2x8.5 KB
    __shared__ float sthr[BROWS];

    const int tid   = threadIdx.x;
    const int lane  = tid & 63;
    const int quad  = lane >> 4;
    const int l15   = lane & 15;
    const int wrow0 = tid & 192;             // wave_id*64
    const int col0  = blockIdx.x * CPB;

    // per-row gate thresholds, computed redundantly per block (x is L2-resident)
    {
        const float* xp = x + (size_t)tid * DDIM;
        float s = 0.f;
#pragma unroll
        for (int k = 0; k < DDIM; k += 4) {
            const float4 v = *(const float4*)(xp + k);
            s = fmaf(v.x, v.x, s); s = fmaf(v.y, v.y, s);
            s = fmaf(v.z, v.z, s); s = fmaf(v.w, v.w, s);
        }
        sthr[tid] = ZGATE * sqrtf(s);
    }

    // A fragments: x fp32 -> bf16 once, register-resident. A[m=l15][k=quad*8+j].
    bf16x8 af[4][4];
#pragma unroll
    for (int mt = 0; mt < 4; ++mt) {
        const float* xp = x + (size_t)(wrow0 + mt * 16 + l15) * DDIM + quad * 8;
#pragma unroll
        for (int s = 0; s < 4; ++s) {
            const float4 a = *(const float4*)(xp + s * 32);
            const float4 b = *(const float4*)(xp + s * 32 + 4);
            const u32x4 t = pack8(a, b);
            af[mt][s] = __builtin_bit_cast(bf16x8, t);
        }
    }

    // staging: thread (scol, skk) loads 16 fp32 (64B) of one col, writes 2 b128
    const int scol = tid >> 3;               // 0..31
    const int skk  = tid & 7;                // 0..7
    const float* ysrc = y + (size_t)(col0 + scol) * DDIM + skk * 16;
    const unsigned sdst = scol * YSTR + skk * 8;        // word offset in a buffer
    const unsigned frag_off = l15 * YSTR + quad * 4;    // + cg*16*YSTR + s*16

    // depth-2 register prefetch: tile t lives in sl[t&1]
    float4 sl[2][4];
#pragma unroll
    for (int q = 0; q < 4; ++q) sl[0][q] = *(const float4*)(ysrc + q * 4);
#pragma unroll
    for (int q = 0; q < 4; ++q) sl[1][q] = *(const float4*)(ysrc + TCOLS * DDIM + q * 4);
    {
        u32x4* d = (u32x4*)(&ybf[0][0] + sdst);
        d[0] = pack8(sl[0][0], sl[0][1]);
        d[1] = pack8(sl[0][2], sl[0][3]);
    }
    __syncthreads();                         // covers sthr + tile0 LDS write

    // per-row gate thresholds for the 16 acc rows this lane owns
    float thrv[16];
#pragma unroll
    for (int mt = 0; mt < 4; ++mt)
#pragma unroll
        for (int r = 0; r < 4; ++r)
            thrv[mt * 4 + r] = sthr[wrow0 + mt * 16 + quad * 4 + r];

#pragma unroll 2
    for (int it = 0; it < NIT; ++it) {
        if (it + 2 < NIT) {                  // issue tile it+2 loads (slot it&1 is free)
            const float* yn = ysrc + (size_t)(it + 2) * TCOLS * DDIM;
#pragma unroll
            for (int q = 0; q < 4; ++q) sl[it & 1][q] = *(const float4*)(yn + q * 4);
        }
        if (it) __syncthreads();             // ybf[it&1] visible; prev reads done

        const unsigned* yb = &ybf[it & 1][0];

        // col-group 0
        f32x4 acc[2][4];
        bf16x8 bfrag[4];
#pragma unroll
        for (int s = 0; s < 4; ++s)
            bfrag[s] = __builtin_bit_cast(bf16x8, *(const u32x4*)(yb + frag_off + s * 16));
#pragma unroll
        for (int mt = 0; mt < 4; ++mt) acc[0][mt] = (f32x4){0.f, 0.f, 0.f, 0.f};
#pragma unroll
        for (int s = 0; s < 4; ++s)
#pragma unroll
            for (int mt = 0; mt < 4; ++mt)
                acc[0][mt] = __builtin_amdgcn_mfma_f32_16x16x32_bf16(af[mt][s], bfrag[s], acc[0][mt], 0, 0, 0);

        if (it + 1 < NIT) {                  // stage tile it+1 into the other buffer
            u32x4* d = (u32x4*)(&ybf[(it + 1) & 1][0] + sdst);
            d[0] = pack8(sl[(it + 1) & 1][0], sl[(it + 1) & 1][1]);
            d[1] = pack8(sl[(it + 1) & 1][2], sl[(it + 1) & 1][3]);
        }

        // col-group 1
#pragma unroll
        for (int s = 0; s < 4; ++s)
            bfrag[s] = __builtin_bit_cast(bf16x8, *(const u32x4*)(yb + 16 * YSTR + frag_off + s * 16));
#pragma unroll
        for (int mt = 0; mt < 4; ++mt) acc[1][mt] = (f32x4){0.f, 0.f, 0.f, 0.f};
#pragma unroll
        for (int s = 0; s < 4; ++s)
#pragma unroll
            for (int mt = 0; mt < 4; ++mt)
                acc[1][mt] = __builtin_amdgcn_mfma_f32_16x16x32_bf16(af[mt][s], bfrag[s], acc[1][mt], 0, 0, 0);

        // collect: lane's 16 acc values of group cg share col = col0+it*32+cg*16+l15.
#pragma unroll
        for (int cg = 0; cg < 2; ++cg) {
            float m = -1.f;
#pragma unroll
            for (int mt = 0; mt < 4; ++mt)
#pragma unroll
                for (int r = 0; r < 4; ++r)
                    m = fmaxf(m, acc[cg][mt][r] - thrv[mt * 4 + r]);
            if (m > 0.f) {
                const int col = col0 + it * TCOLS + cg * 16 + l15;
#pragma unroll
                for (int mt = 0; mt < 4; ++mt)
#pragma unroll
                    for (int r = 0; r < 4; ++r) {
                        const float v = acc[cg][mt][r];
                        if (v > thrv[mt * 4 + r]) {
                            const int row = wrow0 + mt * 16 + quad * 4 + r;
                            const int idx = atomicAdd(&cnt[row], 1);
                            if (idx < CAP) {
                                bufv[row * CAP + idx] = v;
                                bufc[row * CAP + idx] = col;
                            }
                        }
                    }
            }
        }
    }
}

// ---- shared epilogue helpers ------------------------------------------------
__device__ __forceinline__ void insert5(float* t5, float v) {
    if (v > t5[K - 1]) {
        float nv = v;
#pragma unroll
        for (int p = 0; p < K; ++p) {
            const bool gt = nv > t5[p];
            const float tv = t5[p];
            if (gt) { t5[p] = nv; nv = tv; }
        }
    }
}

__device__ __forceinline__ void merge5(float* __restrict__ t5, const float* __restrict__ src) {
#pragma unroll
    for (int p = 0; p < K; ++p) insert5(t5, src[p]);
}

__device__ __forceinline__ float epilogue(const float* t5, float sp) {
    float loss[K], logit[K];
#pragma unroll
    for (int p = 0; p < K; ++p) {
        loss[p]  = fmaxf(0.f, t5[p] - sp + MARGIN);
        logit[p] = (loss[p] != 0.f) ? t5[p] : 0.f;   // sim_n * mask, as reference
    }
    float mx = logit[0];
#pragma unroll
    for (int p = 1; p < K; ++p) mx = fmaxf(mx, logit[p]);
    float den = 0.f, num = 0.f;
#pragma unroll
    for (int p = 0; p < K; ++p) {
        const float e = __expf(logit[p] - mx);
        den += e;
        num += loss[p] * e;
    }
    return num / den;
}

// ---- Pass 2: per-row exact top-5 + loss; brute-force fallback fused in ------
__global__ __launch_bounds__(256) void reduce_kernel(
    const float* __restrict__ x, const float* __restrict__ y,
    const int* __restrict__ pos, const int* __restrict__ cnt,
    const float* __restrict__ simp,
    const float* __restrict__ bufv, const int* __restrict__ bufc,
    float* __restrict__ out)
{
    const int row  = blockIdx.x;
    const int tid  = threadIdx.x;
    const int lane = tid & 63;
    const int wid  = tid >> 6;
    __shared__ float swv[4][K];
    __shared__ float sv[256 * K];
    __shared__ float xr[DDIM];
    __shared__ int   sok;

    const int prow = pos[row];
    const float sp = simp[row];

    const int c = cnt[row];
    const int n = c < CAP ? c : CAP;
    float t5[K];
#pragma unroll
    for (int q = 0; q < K; ++q) t5[q] = -3.0e38f;
    if (tid < n && bufc[row * CAP + tid] != prow)
        t5[0] = bufv[row * CAP + tid];   // one entry per thread (CAP <= 256)

    // per-wave butterfly merge: 6 rounds x (5 shfl + merge5)
#pragma unroll
    for (int off = 1; off < 64; off <<= 1) {
        float o5[K];
#pragma unroll
        for (int q = 0; q < K; ++q) o5[q] = __shfl_xor(t5[q], off);
        merge5(t5, o5);
    }
    if (lane == 0)
#pragma unroll
        for (int q = 0; q < K; ++q) swv[wid][q] = t5[q];
    __syncthreads();

    if (tid == 0) {
#pragma unroll
        for (int w = 1; w < 4; ++w) merge5(t5, swv[w]);
        // exact iff no overflow and >=5 valid survivors
        sok = (c <= CAP && t5[K - 1] > -1.0e38f) ? 1 : 0;
        if (sok) atomicAdd(out, epilogue(t5, sp) * (1.0f / (BROWS * K)));
    }
    __syncthreads();
    if (sok) return;

    // ---- brute-force insurance (statistically never taken; exactness) ------
    if (tid < DDIM) xr[tid] = x[row * DDIM + tid];
    __syncthreads();

#pragma unroll
    for (int q = 0; q < K; ++q) t5[q] = -3.0e38f;
    for (int col = tid; col < NCOLS; col += 256) {
        if (col == prow) continue;
        const float* yp = y + (size_t)col * DDIM;
        float d = 0.f;
        for (int k = 0; k < DDIM; ++k) d = fmaf(xr[k], yp[k], d);
        insert5(t5, d);
    }
#pragma unroll
    for (int q = 0; q < K; ++q) sv[tid * K + q] = t5[q];
    __syncthreads();
    for (int s = 128; s >= 1; s >>= 1) {
        if (tid < s) {
            merge5(t5, &sv[(tid + s) * K]);
#pragma unroll
            for (int q = 0; q < K; ++q) sv[tid * K + q] = t5[q];
        }
        __syncthreads();
    }
    if (tid == 0) atomicAdd(out, epilogue(t5, sp) * (1.0f / (BROWS * K)));
}

extern "C" void kernel_launch(void* const* d_in, const int* in_sizes, int n_in,
                              void* d_out, int out_size, void* d_ws, size_t ws_size,
                              hipStream_t stream) {
    const float* x  = (const float*)d_in[0];   // [256,128] fp32
    const float* y  = (const float*)d_in[1];   // [131072,128] fp32
    // d_in[2] (target) is redundant (one-hot of pos_inds) — never read.
    const int* pos  = (const int*)d_in[3];     // [256] int32
    // d_in[4] (num_neg) fixed at 5 — compile-time K.

    int*   cnt  = (int*)d_ws;                          // 256 ints
    float* simp = (float*)(cnt + BROWS);               // 256 floats
    float* bufv = simp + BROWS;                        // 256*CAP floats (128 KB)
    int*   bufc = (int*)(bufv + (size_t)BROWS * CAP);  // 256*CAP ints

    init_kernel<<<dim3(BROWS), 64, 0, stream>>>(x, y, pos, cnt, simp, (float*)d_out);
    gemm_collect_kernel<<<dim3(NBLK), 256, 0, stream>>>(x, y, cnt, bufv, bufc);
    reduce_kernel<<<dim3(BROWS), 256, 0, stream>>>(x, y, pos, cnt, simp, bufv, bufc, (float*)d_out);
}